// Round 1
// baseline (815.070 us; speedup 1.0000x reference)
//
#include <hip/hip_runtime.h>

namespace {

constexpr int N = 29;
constexpr int K = 6;
constexpr int D = 12;
constexpr int M = 32;
constexpr int EINDIM = 25;
constexpr int H1 = 50;
constexpr int NHID = 24;    // node hidden = 2*D
constexpr int HHID = 32;    // head hidden
constexpr int ODIM = 24;    // head out = 2*D
constexpr int NEDGE = N * K;              // 174
constexpr int EITERS = (NEDGE + 7) / 8;   // 22

__device__ __forceinline__ float sigmoidf_(float v) { return 1.0f / (1.0f + __expf(-v)); }
__device__ __forceinline__ float siluf_(float v) { return v * sigmoidf_(v); }

__global__ __launch_bounds__(256) void arnet_fused(
    const float* __restrict__ x, const float* __restrict__ ctx,
    const float* __restrict__ ew1, const float* __restrict__ eb1,
    const float* __restrict__ ew2, const float* __restrict__ eb2,
    const float* __restrict__ gw, const float* __restrict__ gb,
    const float* __restrict__ nw1, const float* __restrict__ nb1,
    const float* __restrict__ nw2, const float* __restrict__ nb2,
    const float* __restrict__ hw1, const float* __restrict__ hb1,
    const float* __restrict__ hw2, const float* __restrict__ hb2,
    float* __restrict__ out)
{
  // weights (LDS-resident, loaded once per block; L2 serves the global reads)
  __shared__ float s_w1[EINDIM][64];   // e_w1 [25][50] padded to 64 (float2 lane reads)
  __shared__ float s_b1[H1];
  __shared__ float s_w2[H1][M];
  __shared__ float s_b2[M];
  __shared__ float s_gw[M];
  __shared__ float s_gb;
  __shared__ float s_nw1[D + M][NHID];
  __shared__ float s_nb1[NHID];
  __shared__ float s_nw2[NHID][D];
  __shared__ float s_nb2[D];
  __shared__ float s_hw1[D][HHID];
  __shared__ float s_hb1[HHID];
  __shared__ float s_hw2[HHID][ODIM];
  __shared__ float s_hb2[ODIM];
  // per-batch state
  __shared__ float s_ctx[N][4];
  __shared__ float s_feat[N][D];
  __shared__ float s_dist[N][32];
  __shared__ int   s_nbhd[N][K];
  __shared__ float s_rdist[N][K];
  __shared__ float s_h1[8][52];        // per-group edge hidden (50, padded)
  __shared__ float s_mi[N][M];
  __shared__ float s_nh1[N][NHID];
  __shared__ float s_nout[N][D];
  __shared__ float s_pool[D];
  __shared__ float s_hid[HHID];
  __shared__ float s_res[ODIM];

  const int tid = threadIdx.x;
  const int b = blockIdx.x;

  // ---- stage weights ----
  for (int i = tid; i < EINDIM * H1; i += 256) s_w1[i / H1][i % H1] = ew1[i];
  for (int i = tid; i < H1; i += 256) s_b1[i] = eb1[i];
  for (int i = tid; i < H1 * M; i += 256) s_w2[i / M][i % M] = ew2[i];
  for (int i = tid; i < M; i += 256) { s_b2[i] = eb2[i]; s_gw[i] = gw[i]; }
  if (tid == 0) s_gb = gb[0];
  for (int i = tid; i < (D + M) * NHID; i += 256) s_nw1[i / NHID][i % NHID] = nw1[i];
  for (int i = tid; i < NHID; i += 256) s_nb1[i] = nb1[i];
  for (int i = tid; i < NHID * D; i += 256) s_nw2[i / D][i % D] = nw2[i];
  for (int i = tid; i < D; i += 256) s_nb2[i] = nb2[i];
  for (int i = tid; i < D * HHID; i += 256) s_hw1[i / HHID][i % HHID] = hw1[i];
  for (int i = tid; i < HHID; i += 256) s_hb1[i] = hb1[i];
  for (int i = tid; i < HHID * ODIM; i += 256) s_hw2[i / ODIM][i % ODIM] = hw2[i];
  for (int i = tid; i < ODIM; i += 256) s_hb2[i] = hb2[i];

  // ---- stage per-batch inputs ----
  for (int i = tid; i < N * D; i += 256) {
    int r = i / D, c = i - r * D;
    s_feat[r][c] = x[(size_t)b * (N * 6) + r * 6 + (c % 6)];   // feats = concat([x,x])
  }
  for (int i = tid; i < N * 3; i += 256) {
    int r = i / 3, c = i - r * 3;
    s_ctx[r][c] = ctx[(size_t)b * (N * 3) + i];
  }
  for (int i = tid; i < N * M; i += 256) s_mi[i / M][i % M] = 0.0f;
  __syncthreads();

  // ---- pairwise squared distances ----
  for (int i = tid; i < N * N; i += 256) {
    int r = i / N, c = i - r * N;
    float dx = s_ctx[r][0] - s_ctx[c][0];
    float dy = s_ctx[r][1] - s_ctx[c][1];
    float dz = s_ctx[r][2] - s_ctx[c][2];
    s_dist[r][c] = dx * dx + dy * dy + dz * dz;
  }
  __syncthreads();

  // ---- kNN: 6 smallest per row, ties -> lower index (stable top_k semantics) ----
  if (tid < N) {
    unsigned used = 0u;
    for (int k = 0; k < K; ++k) {
      float best = 3.4e38f; int bj = 0;
      for (int j = 0; j < N; ++j) {
        if (used & (1u << j)) continue;
        float dv = s_dist[tid][j];
        if (dv < best) { best = dv; bj = j; }
      }
      used |= (1u << bj);
      s_nbhd[tid][k] = bj;
      s_rdist[tid][k] = best;
    }
  }
  __syncthreads();

  // ---- edge MLP: 8 groups x 32 lanes, one edge per group per iteration ----
  const int g = tid >> 5, t = tid & 31;
  for (int it = 0; it < EITERS; ++it) {
    const int e = it * 8 + g;
    const bool act = e < NEDGE;
    int ei = 0, ej = 0; float rd = 0.0f;
    if (act) {
      ei = e / K; int kk = e - ei * K;
      ej = s_nbhd[ei][kk]; rd = s_rdist[ei][kk];
    }
    if (act && t < EINDIM) {     // lane t computes hidden outputs 2t, 2t+1
      float ein[EINDIM];
      #pragma unroll
      for (int c = 0; c < D; ++c) ein[c] = s_feat[ei][c];
      #pragma unroll
      for (int c = 0; c < D; ++c) ein[D + c] = s_feat[ej][c];
      ein[24] = rd;
      float a0 = s_b1[2 * t], a1 = s_b1[2 * t + 1];
      #pragma unroll
      for (int c = 0; c < EINDIM; ++c) {
        float2 w = ((const float2*)(&s_w1[c][0]))[t];
        a0 = fmaf(ein[c], w.x, a0);
        a1 = fmaf(ein[c], w.y, a1);
      }
      ((float2*)(&s_h1[g][0]))[t] = make_float2(siluf_(a0), siluf_(a1));
    }
    __syncthreads();
    float mc = 0.0f, p = 0.0f;
    if (act) {
      mc = s_b2[t];
      #pragma unroll
      for (int h = 0; h < H1; ++h) mc = fmaf(s_h1[g][h], s_w2[h][t], mc);
      mc = siluf_(mc);
      p = mc * s_gw[t];
    }
    #pragma unroll
    for (int off = 16; off > 0; off >>= 1) p += __shfl_xor(p, off, 32);
    if (act) {
      mc *= sigmoidf_(p + s_gb);          // soft edge gate
      atomicAdd(&s_mi[ei][t], mc);        // scatter-sum over K
    }
    __syncthreads();
  }

  // ---- node MLP (+ residual) ----
  for (int u = tid; u < N * NHID; u += 256) {
    int i = u / NHID, o = u - i * NHID;
    float a = s_nb1[o];
    #pragma unroll
    for (int c = 0; c < D; ++c) a = fmaf(s_feat[i][c], s_nw1[c][o], a);
    #pragma unroll
    for (int c = 0; c < M; ++c) a = fmaf(s_mi[i][c], s_nw1[D + c][o], a);
    s_nh1[i][o] = siluf_(a);
  }
  __syncthreads();
  for (int u = tid; u < N * D; u += 256) {
    int i = u / D, o = u - i * D;
    float a = s_nb2[o];
    #pragma unroll
    for (int h = 0; h < NHID; ++h) a = fmaf(s_nh1[i][h], s_nw2[h][o], a);
    s_nout[i][o] = a + s_feat[i][o];
  }
  __syncthreads();

  // ---- masked mean pool (mask all-ones -> /29) ----
  if (tid < D) {
    float a = 0.0f;
    for (int i = 0; i < N; ++i) a += s_nout[i][tid];
    s_pool[tid] = a / 29.0f;
  }
  __syncthreads();

  // ---- head MLP ----
  if (tid < HHID) {
    float a = s_hb1[tid];
    #pragma unroll
    for (int c = 0; c < D; ++c) a = fmaf(s_pool[c], s_hw1[c][tid], a);
    s_hid[tid] = fmaxf(a, 0.0f);
  }
  __syncthreads();
  if (tid < ODIM) {
    float a = s_hb2[tid];
    #pragma unroll
    for (int h = 0; h < HHID; ++h) a = fmaf(s_hid[h], s_hw2[h][tid], a);
    s_res[tid] = a;
  }
  __syncthreads();

  // ---- write [29][12]: rows 0..1 = head out, rows 2..28 = zero padding ----
  float* ob = out + (size_t)b * (N * D);
  for (int i = tid; i < N * D; i += 256) ob[i] = (i < ODIM) ? s_res[i] : 0.0f;
}

} // namespace

extern "C" void kernel_launch(void* const* d_in, const int* in_sizes, int n_in,
                              void* d_out, int out_size, void* d_ws, size_t ws_size,
                              hipStream_t stream) {
  const float* x   = (const float*)d_in[0];
  const float* ctx = (const float*)d_in[1];
  // d_in[2] = mask: constant all-ones in this problem -> mathematically a no-op
  const float* ew1 = (const float*)d_in[3];
  const float* eb1 = (const float*)d_in[4];
  const float* ew2 = (const float*)d_in[5];
  const float* eb2 = (const float*)d_in[6];
  const float* gw  = (const float*)d_in[7];
  const float* gb  = (const float*)d_in[8];
  const float* nw1 = (const float*)d_in[9];
  const float* nb1 = (const float*)d_in[10];
  const float* nw2 = (const float*)d_in[11];
  const float* nb2 = (const float*)d_in[12];
  const float* hw1 = (const float*)d_in[13];
  const float* hb1 = (const float*)d_in[14];
  const float* hw2 = (const float*)d_in[15];
  const float* hb2 = (const float*)d_in[16];
  float* o = (float*)d_out;

  hipLaunchKernelGGL(arnet_fused, dim3(8192), dim3(256), 0, stream,
                     x, ctx, ew1, eb1, ew2, eb2, gw, gb, nw1, nb1, nw2, nb2,
                     hw1, hb1, hw2, hb2, o);
}

// Round 3
// 625.481 us; speedup vs baseline: 1.3031x; 1.3031x over previous
//
#include <hip/hip_runtime.h>

namespace {

constexpr int N = 29;
constexpr int K = 6;
constexpr int D = 12;
constexpr int M = 32;
constexpr int H1 = 50;
constexpr int NHID = 24;    // node hidden = 2*D
constexpr int HHID = 32;    // head hidden
constexpr int ODIM = 24;    // head out = 2*D
constexpr int NEDGE = N * K;              // 174
constexpr int EITERS = (NEDGE + 7) / 8;   // 22

__device__ __forceinline__ float sigmoidf_(float v) { return 1.0f / (1.0f + __expf(-v)); }
__device__ __forceinline__ float siluf_(float v) { return v * sigmoidf_(v); }

__global__ __launch_bounds__(256) void arnet_fused(
    const float* __restrict__ x, const float* __restrict__ ctx,
    const float* __restrict__ ew1, const float* __restrict__ eb1,
    const float* __restrict__ ew2, const float* __restrict__ eb2,
    const float* __restrict__ gw, const float* __restrict__ gb,
    const float* __restrict__ nw1, const float* __restrict__ nb1,
    const float* __restrict__ nw2, const float* __restrict__ nb2,
    const float* __restrict__ hw1, const float* __restrict__ hb1,
    const float* __restrict__ hw2, const float* __restrict__ hb2,
    float* __restrict__ out)
{
  // node/head weights stay in LDS (small, broadcast-read)
  __shared__ float s_nw1[D + M][NHID];
  __shared__ float s_nb1[NHID];
  __shared__ float s_nw2[NHID][D];
  __shared__ float s_nb2[D];
  __shared__ float s_hw1[D][HHID];
  __shared__ float s_hb1[HHID];
  __shared__ float s_hw2[HHID][ODIM];
  __shared__ float s_hb2[ODIM];
  // per-batch state
  __shared__ float s_ctx[N][4];
  __shared__ float s_feat[N][D];        // row stride 48B: float4-aligned
  __shared__ float s_dist[N][33];       // +1 pad: bank = (33r+j)%32 -> conflict-free column scans
  __shared__ int   s_nbhd[N][K];
  __shared__ float s_rdist[N][K];
  __shared__ float s_h1[8][56];         // per-group edge hidden (50, padded to 56 for f4 + bank-skew)
  __shared__ float s_mi[N][M];
  __shared__ float s_nh1[N][NHID];
  __shared__ float s_nout[N][D];
  __shared__ float s_pool[D];
  __shared__ float s_hid[HHID];
  __shared__ float s_res[ODIM];

  const int tid = threadIdx.x;
  const int b = blockIdx.x;
  const int g = tid >> 5, t = tid & 31;

  // ---- edge-MLP weights -> REGISTERS (loaded once, reused for all 22 edges) ----
  // lane t owns hidden channels 2t,2t+1 (layer 1) and output channel t (layer 2).
  const int tc = (t < 25) ? t : 24;     // clamp to stay in-bounds; lanes 25..31 hold dup data
  float2 w1r[25];
  #pragma unroll
  for (int c = 0; c < 25; ++c)
    w1r[c] = *(const float2*)(ew1 + c * H1 + 2 * tc);
  const float2 b1r = *(const float2*)(eb1 + 2 * tc);
  float w2r[H1];
  #pragma unroll
  for (int h = 0; h < H1; ++h) w2r[h] = ew2[h * M + t];
  const float b2r = eb2[t];
  const float gwr = gw[t];
  const float gbr = gb[0];

  // ---- stage LDS weights ----
  for (int i = tid; i < (D + M) * NHID; i += 256) s_nw1[i / NHID][i % NHID] = nw1[i];
  for (int i = tid; i < NHID; i += 256) s_nb1[i] = nb1[i];
  for (int i = tid; i < NHID * D; i += 256) s_nw2[i / D][i % D] = nw2[i];
  for (int i = tid; i < D; i += 256) s_nb2[i] = nb2[i];
  for (int i = tid; i < D * HHID; i += 256) s_hw1[i / HHID][i % HHID] = hw1[i];
  for (int i = tid; i < HHID; i += 256) s_hb1[i] = hb1[i];
  for (int i = tid; i < HHID * ODIM; i += 256) s_hw2[i / ODIM][i % ODIM] = hw2[i];
  for (int i = tid; i < ODIM; i += 256) s_hb2[i] = hb2[i];

  // ---- stage per-batch inputs ----
  for (int i = tid; i < N * D; i += 256) {
    int r = i / D, c = i - r * D;
    s_feat[r][c] = x[(size_t)b * (N * 6) + r * 6 + (c % 6)];   // feats = concat([x,x])
  }
  for (int i = tid; i < N * 3; i += 256)
    s_ctx[i / 3][i % 3] = ctx[(size_t)b * (N * 3) + i];
  for (int i = tid; i < N * M; i += 256) s_mi[i / M][i % M] = 0.0f;
  __syncthreads();

  // ---- pairwise squared distances ----
  for (int i = tid; i < N * N; i += 256) {
    int r = i / N, c = i - r * N;
    float dx = s_ctx[r][0] - s_ctx[c][0];
    float dy = s_ctx[r][1] - s_ctx[c][1];
    float dz = s_ctx[r][2] - s_ctx[c][2];
    s_dist[r][c] = dx * dx + dy * dy + dz * dz;
  }
  __syncthreads();

  // ---- kNN: 6 smallest per row, ties -> lower index (stable top_k semantics) ----
  if (tid < N) {
    unsigned used = 0u;
    for (int k = 0; k < K; ++k) {
      float best = 3.4e38f; int bj = 0;
      for (int j = 0; j < N; ++j) {
        if (used & (1u << j)) continue;
        float dv = s_dist[tid][j];
        if (dv < best) { best = dv; bj = j; }
      }
      used |= (1u << bj);
      s_nbhd[tid][k] = bj;
      s_rdist[tid][k] = best;
    }
  }
  __syncthreads();

  // ---- edge MLP: 8 groups (= 2 per wave64), NO block barriers in this loop.
  // Each group's s_h1 row is produced & consumed by the same wave -> lgkmcnt
  // ordering suffices; cross-group output only via commutative atomicAdd.
  #pragma unroll 1
  for (int it = 0; it < EITERS; ++it) {
    const int e = it * 8 + g;
    const bool act = e < NEDGE;
    if (act) {
      const int ei = e / K, kk = e - (e / K) * K;
      const int ej = s_nbhd[ei][kk];
      const float rd = s_rdist[ei][kk];

      // layer 1: all 32 lanes compute (lanes >=25 produce dup garbage, not stored)
      float a0 = b1r.x, a1 = b1r.y;
      const float4* fi4 = (const float4*)(&s_feat[ei][0]);
      const float4* fj4 = (const float4*)(&s_feat[ej][0]);
      #pragma unroll
      for (int p = 0; p < 3; ++p) {
        float4 f = fi4[p];
        a0 = fmaf(f.x, w1r[4*p+0].x, a0); a1 = fmaf(f.x, w1r[4*p+0].y, a1);
        a0 = fmaf(f.y, w1r[4*p+1].x, a0); a1 = fmaf(f.y, w1r[4*p+1].y, a1);
        a0 = fmaf(f.z, w1r[4*p+2].x, a0); a1 = fmaf(f.z, w1r[4*p+2].y, a1);
        a0 = fmaf(f.w, w1r[4*p+3].x, a0); a1 = fmaf(f.w, w1r[4*p+3].y, a1);
      }
      #pragma unroll
      for (int p = 0; p < 3; ++p) {
        float4 f = fj4[p];
        a0 = fmaf(f.x, w1r[12+4*p+0].x, a0); a1 = fmaf(f.x, w1r[12+4*p+0].y, a1);
        a0 = fmaf(f.y, w1r[12+4*p+1].x, a0); a1 = fmaf(f.y, w1r[12+4*p+1].y, a1);
        a0 = fmaf(f.z, w1r[12+4*p+2].x, a0); a1 = fmaf(f.z, w1r[12+4*p+2].y, a1);
        a0 = fmaf(f.w, w1r[12+4*p+3].x, a0); a1 = fmaf(f.w, w1r[12+4*p+3].y, a1);
      }
      a0 = fmaf(rd, w1r[24].x, a0); a1 = fmaf(rd, w1r[24].y, a1);
      if (t < 25)
        ((float2*)(&s_h1[g][0]))[t] = make_float2(siluf_(a0), siluf_(a1));

      // layer 2: 13 broadcast f4/f2 reads (LGKM, overlapped) + 50 FMA with reg weights
      float mc = b2r;
      const float4* h4 = (const float4*)(&s_h1[g][0]);
      #pragma unroll
      for (int hv = 0; hv < 12; ++hv) {
        float4 h = h4[hv];
        mc = fmaf(h.x, w2r[4*hv+0], mc);
        mc = fmaf(h.y, w2r[4*hv+1], mc);
        mc = fmaf(h.z, w2r[4*hv+2], mc);
        mc = fmaf(h.w, w2r[4*hv+3], mc);
      }
      {
        float2 ht = ((const float2*)(&s_h1[g][0]))[24];
        mc = fmaf(ht.x, w2r[48], mc);
        mc = fmaf(ht.y, w2r[49], mc);
      }
      mc = siluf_(mc);

      // soft edge gate: group-wide dot(m, gw) via shuffle reduce
      float p = mc * gwr;
      #pragma unroll
      for (int off = 16; off > 0; off >>= 1) p += __shfl_xor(p, off, 32);
      mc *= sigmoidf_(p + gbr);
      atomicAdd(&s_mi[ei][t], mc);        // scatter-sum over K neighbors
    }
  }
  __syncthreads();

  // ---- node MLP (+ residual) ----
  for (int u = tid; u < N * NHID; u += 256) {
    int i = u / NHID, o = u - i * NHID;
    float a = s_nb1[o];
    #pragma unroll
    for (int c = 0; c < D; ++c) a = fmaf(s_feat[i][c], s_nw1[c][o], a);
    #pragma unroll
    for (int c = 0; c < M; ++c) a = fmaf(s_mi[i][c], s_nw1[D + c][o], a);
    s_nh1[i][o] = siluf_(a);
  }
  __syncthreads();
  for (int u = tid; u < N * D; u += 256) {
    int i = u / D, o = u - i * D;
    float a = s_nb2[o];
    #pragma unroll
    for (int h = 0; h < NHID; ++h) a = fmaf(s_nh1[i][h], s_nw2[h][o], a);
    s_nout[i][o] = a + s_feat[i][o];
  }
  __syncthreads();

  // ---- masked mean pool (mask all-ones -> /29) ----
  if (tid < D) {
    float a = 0.0f;
    for (int i = 0; i < N; ++i) a += s_nout[i][tid];
    s_pool[tid] = a / 29.0f;
  }
  __syncthreads();

  // ---- head MLP ----
  if (tid < HHID) {
    float a = s_hb1[tid];
    #pragma unroll
    for (int c = 0; c < D; ++c) a = fmaf(s_pool[c], s_hw1[c][tid], a);
    s_hid[tid] = fmaxf(a, 0.0f);
  }
  __syncthreads();
  if (tid < ODIM) {
    float a = s_hb2[tid];
    #pragma unroll
    for (int h = 0; h < HHID; ++h) a = fmaf(s_hid[h], s_hw2[h][tid], a);
    s_res[tid] = a;
  }
  __syncthreads();

  // ---- write [29][12]: rows 0..1 = head out, rows 2..28 = zero padding ----
  float* ob = out + (size_t)b * (N * D);
  for (int i = tid; i < N * D; i += 256) ob[i] = (i < ODIM) ? s_res[i] : 0.0f;
}

} // namespace

extern "C" void kernel_launch(void* const* d_in, const int* in_sizes, int n_in,
                              void* d_out, int out_size, void* d_ws, size_t ws_size,
                              hipStream_t stream) {
  const float* x   = (const float*)d_in[0];
  const float* ctx = (const float*)d_in[1];
  // d_in[2] = mask: constant all-ones in this problem -> mathematically a no-op
  const float* ew1 = (const float*)d_in[3];
  const float* eb1 = (const float*)d_in[4];
  const float* ew2 = (const float*)d_in[5];
  const float* eb2 = (const float*)d_in[6];
  const float* gw  = (const float*)d_in[7];
  const float* gb  = (const float*)d_in[8];
  const float* nw1 = (const float*)d_in[9];
  const float* nb1 = (const float*)d_in[10];
  const float* nw2 = (const float*)d_in[11];
  const float* nb2 = (const float*)d_in[12];
  const float* hw1 = (const float*)d_in[13];
  const float* hb1 = (const float*)d_in[14];
  const float* hw2 = (const float*)d_in[15];
  const float* hb2 = (const float*)d_in[16];
  float* o = (float*)d_out;

  hipLaunchKernelGGL(arnet_fused, dim3(8192), dim3(256), 0, stream,
                     x, ctx, ew1, eb1, ew2, eb2, gw, gb, nw1, nb1, nw2, nb2,
                     hw1, hb1, hw2, hb2, o);
}